// Round 15
// baseline (52651.611 us; speedup 1.0000x reference)
//
#include <hip/hip_runtime.h>
#include <hip/hip_fp16.h>
#include <hip/hip_cooperative_groups.h>
#include <stdint.h>

#define TIME_STEPS 4096
#define DIM        2048
#define NBLK       256    // grid (co-resident: 1 block/CU)
#define NTH        512    // 8 waves per block
#define NWORK      32     // worker blocks (one XCD's worth of CUs)
#define WVB        8      // waves per worker block
#define RPW        8      // rows per wave: 256 waves x 8 = 2048

typedef uint32_t u32x4 __attribute__((ext_vector_type(4)));
typedef _Float16 h2f16 __attribute__((ext_vector_type(2)));

// actbuf entry: u32 = (tag16<<16)|fp16bits(act); slot t%NSLOT holds gen t
// (tag=t+1). Validity: min over dwords >= tag<<16.
// r15: flag-gated per-chunk compute. Each staging wave wv sets LDS
// flag[b][wv]=t+1 after lgkmcnt(0) (per-WAVE counter -> all 64 lanes'
// ds_writes complete). Lanes consume 16 pairs from EACH of the 8 chunks,
// own chunk first -> compute overlaps the arrival skew of late chunks.
// __syncthreads moves to end-of-step (2 barriers still separate any lds[b]
// read from its next overwrite -> WAR-safe; intra-block drift < 1 step).
// d_ws: ring | progress[NWORK] | xccmap[NBLK]

__device__ __forceinline__ uint32_t umin32(uint32_t a, uint32_t b) { return a < b ? a : b; }

__device__ __forceinline__ float dot2f(uint32_t packed, h2f16 w, float acc) {
#if __has_builtin(__builtin_amdgcn_fdot2)
  return __builtin_amdgcn_fdot2(__builtin_bit_cast(h2f16, packed), w, acc, false);
#else
  h2f16 a = __builtin_bit_cast(h2f16, packed);
  acc = fmaf((float)a.x, (float)w.x, acc);
  return fmaf((float)a.y, (float)w.y, acc);
#endif
}

// Pair-index swizzle: p ^ (((p>>4)&7)<<2). For reads at p=k*128+g*16+4j the
// xor term is g<<2 -> banks (16g+4j+4g)%32 = (20g+4j)%32: 8 g-groups land on
// 8 distinct bank-quads (conflict-free). Preserves bits[1:0] (b128 align).
__device__ __forceinline__ int swz3(int p) { return p ^ (((p >> 4) & 7) << 2); }

#define POLL_ISSUE(dst, src)                                       \
  asm volatile("global_load_dwordx4 %0, %1, off sc1"               \
               : "=&v"(dst) : "v"(src) : "memory")

template<int NSLOT>
__global__ __launch_bounds__(NTH, 2) void ctrnn_kernel(
    const float* __restrict__ x,        // [TIME, DIM]
    const float* __restrict__ W,        // [DIM, DIM]
    const float* __restrict__ bias,     // [DIM]
    const float* __restrict__ initial,  // [DIM]
    float* __restrict__ out,            // [TIME, DIM]
    uint32_t* __restrict__ actbuf,
    uint32_t* __restrict__ progress,
    uint32_t* __restrict__ xccmap)
{
  const int tid  = threadIdx.x;
  const int lane = tid & 63;
  const int wv   = tid >> 6;            // wave in block (0..7)

  // ---- phase 0: report this block's XCD ----
  if (tid == 0) {
    uint32_t xcc;
    asm volatile("s_getreg_b32 %0, hwreg(HW_REG_XCC_ID)" : "=s"(xcc));
    __hip_atomic_store(&xccmap[blockIdx.x], xcc,
                       __ATOMIC_RELAXED, __HIP_MEMORY_SCOPE_AGENT);
  }
  cooperative_groups::this_grid().sync();

  // ---- phase 1: deterministic election (bijective rank permutation) ----
  __shared__ uint32_t s_map[NBLK];
  for (int i = tid; i < NBLK; i += NTH)
    s_map[i] = __hip_atomic_load(&xccmap[i], __ATOMIC_RELAXED, __HIP_MEMORY_SCOPE_AGENT);
  __syncthreads();
  const uint32_t target = s_map[0];
  int before = 0, total = 0, beforeN = 0;
  const int bid = blockIdx.x;
  for (int i = 0; i < NBLK; ++i) {
    const bool m = (s_map[i] == target);
    total += m;
    if (i < bid) { before += m; beforeN += !m; }
  }
  const bool mine = (s_map[bid] == target);
  const int rank = mine ? before : (total + beforeN);
  if (rank >= NWORK) return;            // 224 blocks exit; no further grid syncs
  const int wb = rank;

  __shared__ uint32_t lds[2][1024];     // packed fp16-pair acts, swz3 layout
  __shared__ uint32_t flags[2][8];      // per-chunk staged-generation flags
  if (tid < 16) ((uint32_t*)flags)[tid] = 0;
  __syncthreads();

  const int gwid = wb * WVB + wv;       // worker wave id 0..255
  const int row0 = gwid * RPW;

  // Lane roles: r_ = row within wave's 8; g_ = col-group. Lane handles, for
  // every chunk k, pairs [k*128+g_*16, +16) of row row0+r_.
  const int r_ = lane & 7;
  const int g_ = lane >> 3;

  // W fragment fp16x2: 8 chunks x 16 pairs = 128 VGPRs.
  h2f16 w2[8][16];
  #pragma unroll
  for (int k = 0; k < 8; ++k) {
    const float* wr = W + (size_t)(row0 + r_) * DIM + k * 256 + g_ * 32;
    #pragma unroll
    for (int q = 0; q < 16; ++q)
      w2[k][q] = h2f16{(_Float16)wr[2*q], (_Float16)wr[2*q+1]};
  }

  // ---- batched x window: [t0, t0+16), 2 VGPRs/lane (r13) ----
  const int xq = lane >> 3, xr = lane & 7;
  float xa = x[(size_t)xq * DIM + row0 + xr];
  float xb = x[(size_t)(8 + xq) * DIM + row0 + xr];
  float xa2 = 0.f, xb2 = 0.f;
  int t0 = 0;

  // State: lanes 0..7 own rows row0..row0+7.
  float v = 0.f, bj = 0.f;
  if (lane < RPW) {
    const int j = row0 + lane;
    v  = initial[j];
    bj = bias[j];
    out[j] = v;
    const float a0 = 1.0f / (1.0f + __expf(-(v + bj)));
    __half h = __float2half_rn(a0);
    uint16_t hb; __builtin_memcpy(&hb, &h, 2);
    __hip_atomic_store(&actbuf[j], (1u << 16) | hb,
                       __ATOMIC_RELAXED, __HIP_MEMORY_SCOPE_AGENT);
  }

  // Staging geometry: wave wv owns entries [wv*256, +256); lane's quad at e0,
  // pairs p0 = wv*128 + lane*2 (even; swz3 keeps +1 contiguous).
  const int e0 = wv * 256 + lane * 4;
  const int p0 = wv * 128 + lane * 2;

  uint32_t prog_seen = 0;

  for (int t = 0; t < TIME_STEPS - 1; ++t) {
    const int b = t & 1;
    const int off = t - t0;
    const uint32_t needtag = (uint32_t)(t + 1);
    const uint32_t thresh  = needtag << 16;

    // ---- 2-deep ping-pong poll of own quad (sc1) ----
    const uint32_t* qsrc = actbuf + (size_t)(t & (NSLOT - 1)) * DIM + e0;
    u32x4 qa, qb, q;
    POLL_ISSUE(qa, qsrc);
    POLL_ISSUE(qb, qsrc);
    for (;;) {
      asm volatile("s_waitcnt vmcnt(1)" ::: "memory");
      __builtin_amdgcn_sched_barrier(0);
      if (umin32(umin32(qa[0], qa[1]), umin32(qa[2], qa[3])) >= thresh) { q = qa; break; }
      POLL_ISSUE(qa, qsrc);
      asm volatile("s_waitcnt vmcnt(1)" ::: "memory");
      __builtin_amdgcn_sched_barrier(0);
      if (umin32(umin32(qb[0], qb[1]), umin32(qb[2], qb[3])) >= thresh) { q = qb; break; }
      POLL_ISSUE(qb, qsrc);
    }
    asm volatile("s_waitcnt vmcnt(0)" ::: "memory");   // retire strays (reg reuse)
    __builtin_amdgcn_sched_barrier(0);

    // ---- stage packed fp16 pairs into swz3 LDS, then set chunk flag ----
    {
      const uint32_t lo = __builtin_amdgcn_perm(q[1], q[0], 0x05040100u);
      const uint32_t hi = __builtin_amdgcn_perm(q[3], q[2], 0x05040100u);
      const int w0 = swz3(p0);
      lds[b][w0]     = lo;
      lds[b][w0 + 1] = hi;
    }
    asm volatile("s_waitcnt lgkmcnt(0)" ::: "memory");  // whole wave's ds_writes done
    if (lane == 0)
      __hip_atomic_store(&flags[b][wv], needtag,
                         __ATOMIC_RELAXED, __HIP_MEMORY_SCOPE_WORKGROUP);

    if (tid == 0)
      __hip_atomic_store(&progress[wb], needtag,
                         __ATOMIC_RELAXED, __HIP_MEMORY_SCOPE_AGENT);

    // ---- x window refill (once per 16 steps) ----
    if (off == 13) {
      const int ta = min(t0 + 16 + xq, TIME_STEPS - 1);
      const int tb = min(t0 + 24 + xq, TIME_STEPS - 1);
      xa2 = x[(size_t)ta * DIM + row0 + xr];
      xb2 = x[(size_t)tb * DIM + row0 + xr];
    }

    // ---- flag-gated chunk compute (own chunk first, no wait) ----
    float ac0 = 0.f, ac1 = 0.f, ac2 = 0.f, ac3 = 0.f;
    #pragma unroll
    for (int i = 0; i < 8; ++i) {
      const int k = (wv + i) & 7;
      if (i > 0) {
        while (__hip_atomic_load(&flags[b][k], __ATOMIC_ACQUIRE,
                                 __HIP_MEMORY_SCOPE_WORKGROUP) < needtag) { }
        __builtin_amdgcn_sched_barrier(0);
      }
      const int base = k * 128 + g_ * 16;
      #pragma unroll
      for (int j = 0; j < 4; ++j) {
        const u32x4 qq = *reinterpret_cast<const u32x4*>(&lds[b][swz3(base + 4 * j)]);
        ac0 = dot2f(qq[0], w2[k][4*j+0], ac0);
        ac1 = dot2f(qq[1], w2[k][4*j+1], ac1);
        ac2 = dot2f(qq[2], w2[k][4*j+2], ac2);
        ac3 = dot2f(qq[3], w2[k][4*j+3], ac3);
      }
    }
    float p = (ac0 + ac1) + (ac2 + ac3);
    // fold over g (bits 3,4,5): lane l ends with row (l&7) total
    p += __shfl_xor(p, 8, 64);
    p += __shfl_xor(p, 16, 64);
    p += __shfl_xor(p, 32, 64);

    // ---- WAR gate: fires ~every NSLOT-1 steps ----
    if (t >= NSLOT - 1) {
      const uint32_t need = (uint32_t)(t + 2 - NSLOT);
      if (need > prog_seen) {
        for (;;) {
          uint32_t mn = __hip_atomic_load(&progress[lane & (NWORK - 1)],
                            __ATOMIC_RELAXED, __HIP_MEMORY_SCOPE_AGENT);
          uint32_t qv;
          qv = (uint32_t)__shfl_xor((int)mn, 1, 64);  mn = umin32(mn, qv);
          qv = (uint32_t)__shfl_xor((int)mn, 2, 64);  mn = umin32(mn, qv);
          qv = (uint32_t)__shfl_xor((int)mn, 4, 64);  mn = umin32(mn, qv);
          qv = (uint32_t)__shfl_xor((int)mn, 8, 64);  mn = umin32(mn, qv);
          qv = (uint32_t)__shfl_xor((int)mn, 16, 64); mn = umin32(mn, qv);
          if (mn >= need) { prog_seen = mn; break; }
          __builtin_amdgcn_s_sleep(1);
        }
      }
    }

    // ---- x for this step via one bpermute (window regs, no VMEM) ----
    const float xsrc = (off < 8) ? xa : xb;
    const float xvt  = __shfl(xsrc, ((off & 7) << 3) | xr, 64);

    // ---- state update: publish act FIRST, then out[] store ----
    if (lane < RPW) {
      v = 0.9f * v + 0.1f * (p + xvt);
      const float a = 1.0f / (1.0f + __expf(-(v + bj)));
      __half h = __float2half_rn(a);
      uint16_t hb; __builtin_memcpy(&hb, &h, 2);
      const uint32_t e = ((uint32_t)(t + 2) << 16) | hb;
      __hip_atomic_store(&actbuf[(size_t)((t + 1) & (NSLOT - 1)) * DIM + row0 + lane], e,
                         __ATOMIC_RELAXED, __HIP_MEMORY_SCOPE_AGENT);
      out[(size_t)(t + 1) * DIM + row0 + lane] = v;
    }

    // ---- window swap after last use ----
    if (off == 15) { t0 += 16; xa = xa2; xb = xb2; }

    // ---- end-of-step barrier: bounds intra-block drift (<1 step), provides
    //      WAR safety for lds[b]/flags[b] reuse at t+2 ----
    __syncthreads();
  }
}

extern "C" void kernel_launch(void* const* d_in, const int* in_sizes, int n_in,
                              void* d_out, int out_size, void* d_ws, size_t ws_size,
                              hipStream_t stream) {
  const float* x       = (const float*)d_in[0];
  const float* W       = (const float*)d_in[1];
  const float* bias    = (const float*)d_in[2];
  const float* initial = (const float*)d_in[3];
  float* out           = (float*)d_out;

  uint32_t* actbuf = (uint32_t*)d_ws;

  const size_t need16 = ((size_t)16 * DIM + NWORK + NBLK) * 4;
  const size_t need8  = ((size_t)8  * DIM + NWORK + NBLK) * 4;
  void* kfun;
  size_t ringwords;
  if (ws_size >= need16)     { kfun = (void*)ctrnn_kernel<16>; ringwords = (size_t)16 * DIM; }
  else if (ws_size >= need8) { kfun = (void*)ctrnn_kernel<8>;  ringwords = (size_t)8  * DIM; }
  else                       { kfun = (void*)ctrnn_kernel<2>;  ringwords = (size_t)2  * DIM; }

  uint32_t* progress = actbuf + ringwords;
  uint32_t* xccmap   = progress + NWORK;

  // Tags/progress are generation counters — clear every call (capture-safe).
  hipMemsetAsync(d_ws, 0, (ringwords + NWORK + NBLK) * 4, stream);

  void* args[] = { (void*)&x, (void*)&W, (void*)&bias, (void*)&initial,
                   (void*)&out, (void*)&actbuf, (void*)&progress, (void*)&xccmap };
  hipLaunchCooperativeKernel(kfun, dim3(NBLK), dim3(NTH), args, 0, stream);
}

// Round 16
// 23317.143 us; speedup vs baseline: 2.2581x; 2.2581x over previous
//
#include <hip/hip_runtime.h>
#include <hip/hip_fp16.h>
#include <hip/hip_cooperative_groups.h>
#include <stdint.h>

#define TIME_STEPS 4096
#define DIM        2048
#define NBLK       256    // grid (co-resident: 1 block/CU)
#define NTH        512    // 8 waves per block
#define NWORK      32     // worker blocks (one XCD's worth of CUs)
#define WVB        8      // waves per worker block
#define RPW        8      // rows per wave: 256 waves x 8 = 2048

typedef uint32_t u32x4 __attribute__((ext_vector_type(4)));
typedef _Float16 h2f16 __attribute__((ext_vector_type(2)));

// actbuf entry: u32 = (tag16<<16)|fp16bits(act); slot t%NSLOT holds gen t
// (tag=t+1). Validity: min over dwords >= tag<<16.
// r16 = r15 with STATIC chunk order (rule #20: r15's runtime-indexed w2[k]
// spilled all W registers to scratch -> 21GB HBM streaming). Chunks are
// consumed i=0..7 compile-time; flag[b][i] gates each (own chunk instant,
// early chunks usually already set) -> compute overlaps producer skew.
// d_ws: ring | progress[NWORK] | xccmap[NBLK]

__device__ __forceinline__ uint32_t umin32(uint32_t a, uint32_t b) { return a < b ? a : b; }

__device__ __forceinline__ float dot2f(uint32_t packed, h2f16 w, float acc) {
#if __has_builtin(__builtin_amdgcn_fdot2)
  return __builtin_amdgcn_fdot2(__builtin_bit_cast(h2f16, packed), w, acc, false);
#else
  h2f16 a = __builtin_bit_cast(h2f16, packed);
  acc = fmaf((float)a.x, (float)w.x, acc);
  return fmaf((float)a.y, (float)w.y, acc);
#endif
}

// Pair-index swizzle: p ^ (((p>>4)&7)<<2). Reads at p=k*128+g*16+4j get xor
// term g<<2 -> banks (20g+4j)%32: the 8 g-groups hit 8 distinct bank-quads
// (conflict-free). Preserves bits[1:0] (b128 alignment).
__device__ __forceinline__ int swz3(int p) { return p ^ (((p >> 4) & 7) << 2); }

#define POLL_ISSUE(dst, src)                                       \
  asm volatile("global_load_dwordx4 %0, %1, off sc1"               \
               : "=&v"(dst) : "v"(src) : "memory")

template<int NSLOT>
__global__ __launch_bounds__(NTH, 2) void ctrnn_kernel(
    const float* __restrict__ x,        // [TIME, DIM]
    const float* __restrict__ W,        // [DIM, DIM]
    const float* __restrict__ bias,     // [DIM]
    const float* __restrict__ initial,  // [DIM]
    float* __restrict__ out,            // [TIME, DIM]
    uint32_t* __restrict__ actbuf,
    uint32_t* __restrict__ progress,
    uint32_t* __restrict__ xccmap)
{
  const int tid  = threadIdx.x;
  const int lane = tid & 63;
  const int wv   = tid >> 6;            // wave in block (0..7)

  // ---- phase 0: report this block's XCD ----
  if (tid == 0) {
    uint32_t xcc;
    asm volatile("s_getreg_b32 %0, hwreg(HW_REG_XCC_ID)" : "=s"(xcc));
    __hip_atomic_store(&xccmap[blockIdx.x], xcc,
                       __ATOMIC_RELAXED, __HIP_MEMORY_SCOPE_AGENT);
  }
  cooperative_groups::this_grid().sync();

  // ---- phase 1: deterministic election (bijective rank permutation) ----
  __shared__ uint32_t s_map[NBLK];
  for (int i = tid; i < NBLK; i += NTH)
    s_map[i] = __hip_atomic_load(&xccmap[i], __ATOMIC_RELAXED, __HIP_MEMORY_SCOPE_AGENT);
  __syncthreads();
  const uint32_t target = s_map[0];
  int before = 0, total = 0, beforeN = 0;
  const int bid = blockIdx.x;
  for (int i = 0; i < NBLK; ++i) {
    const bool m = (s_map[i] == target);
    total += m;
    if (i < bid) { before += m; beforeN += !m; }
  }
  const bool mine = (s_map[bid] == target);
  const int rank = mine ? before : (total + beforeN);
  if (rank >= NWORK) return;            // 224 blocks exit; no further grid syncs
  const int wb = rank;

  __shared__ uint32_t lds[2][1024];     // packed fp16-pair acts, swz3 layout
  __shared__ uint32_t flags[2][8];      // per-chunk staged-generation flags
  if (tid < 16) ((uint32_t*)flags)[tid] = 0;
  __syncthreads();

  const int gwid = wb * WVB + wv;       // worker wave id 0..255
  const int row0 = gwid * RPW;

  // Lane roles: r_ = row within wave's 8; g_ = col-group. Lane handles, for
  // every chunk k, pairs [k*128+g_*16, +16) of row row0+r_.
  const int r_ = lane & 7;
  const int g_ = lane >> 3;

  // W fragment fp16x2: 8 chunks x 16 pairs = 128 VGPRs (ALL indices static).
  h2f16 w2[8][16];
  #pragma unroll
  for (int k = 0; k < 8; ++k) {
    const float* wr = W + (size_t)(row0 + r_) * DIM + k * 256 + g_ * 32;
    #pragma unroll
    for (int q = 0; q < 16; ++q)
      w2[k][q] = h2f16{(_Float16)wr[2*q], (_Float16)wr[2*q+1]};
  }

  // ---- batched x window: [t0, t0+16), 2 VGPRs/lane (r13) ----
  const int xq = lane >> 3, xr = lane & 7;
  float xa = x[(size_t)xq * DIM + row0 + xr];
  float xb = x[(size_t)(8 + xq) * DIM + row0 + xr];
  float xa2 = 0.f, xb2 = 0.f;
  int t0 = 0;

  // State: lanes 0..7 own rows row0..row0+7.
  float v = 0.f, bj = 0.f;
  if (lane < RPW) {
    const int j = row0 + lane;
    v  = initial[j];
    bj = bias[j];
    out[j] = v;
    const float a0 = 1.0f / (1.0f + __expf(-(v + bj)));
    __half h = __float2half_rn(a0);
    uint16_t hb; __builtin_memcpy(&hb, &h, 2);
    __hip_atomic_store(&actbuf[j], (1u << 16) | hb,
                       __ATOMIC_RELAXED, __HIP_MEMORY_SCOPE_AGENT);
  }

  // Staging geometry: wave wv owns entries [wv*256, +256); lane's quad at e0,
  // pairs p0 = wv*128 + lane*2 (even; swz3 keeps +1 contiguous).
  const int e0 = wv * 256 + lane * 4;
  const int p0 = wv * 128 + lane * 2;

  uint32_t prog_seen = 0;

  for (int t = 0; t < TIME_STEPS - 1; ++t) {
    const int b = t & 1;
    const int off = t - t0;
    const uint32_t needtag = (uint32_t)(t + 1);
    const uint32_t thresh  = needtag << 16;

    // ---- 2-deep ping-pong poll of own quad (sc1) ----
    const uint32_t* qsrc = actbuf + (size_t)(t & (NSLOT - 1)) * DIM + e0;
    u32x4 qa, qb, q;
    POLL_ISSUE(qa, qsrc);
    POLL_ISSUE(qb, qsrc);
    for (;;) {
      asm volatile("s_waitcnt vmcnt(1)" ::: "memory");
      __builtin_amdgcn_sched_barrier(0);
      if (umin32(umin32(qa[0], qa[1]), umin32(qa[2], qa[3])) >= thresh) { q = qa; break; }
      POLL_ISSUE(qa, qsrc);
      asm volatile("s_waitcnt vmcnt(1)" ::: "memory");
      __builtin_amdgcn_sched_barrier(0);
      if (umin32(umin32(qb[0], qb[1]), umin32(qb[2], qb[3])) >= thresh) { q = qb; break; }
      POLL_ISSUE(qb, qsrc);
    }
    asm volatile("s_waitcnt vmcnt(0)" ::: "memory");   // retire strays (reg reuse)
    __builtin_amdgcn_sched_barrier(0);

    // ---- stage packed fp16 pairs into swz3 LDS, then set chunk flag ----
    {
      const uint32_t lo = __builtin_amdgcn_perm(q[1], q[0], 0x05040100u);
      const uint32_t hi = __builtin_amdgcn_perm(q[3], q[2], 0x05040100u);
      const int w0 = swz3(p0);
      lds[b][w0]     = lo;
      lds[b][w0 + 1] = hi;
    }
    asm volatile("s_waitcnt lgkmcnt(0)" ::: "memory");  // whole wave's ds_writes done
    if (lane == 0)
      __hip_atomic_store(&flags[b][wv], needtag,
                         __ATOMIC_RELAXED, __HIP_MEMORY_SCOPE_WORKGROUP);

    if (tid == 0)
      __hip_atomic_store(&progress[wb], needtag,
                         __ATOMIC_RELAXED, __HIP_MEMORY_SCOPE_AGENT);

    // ---- x window refill (once per 16 steps) ----
    if (off == 13) {
      const int ta = min(t0 + 16 + xq, TIME_STEPS - 1);
      const int tb = min(t0 + 24 + xq, TIME_STEPS - 1);
      xa2 = x[(size_t)ta * DIM + row0 + xr];
      xb2 = x[(size_t)tb * DIM + row0 + xr];
    }

    // ---- flag-gated chunk compute, STATIC order 0..7 (w2 stays in regs) ----
    float ac0 = 0.f, ac1 = 0.f, ac2 = 0.f, ac3 = 0.f;
    #pragma unroll
    for (int i = 0; i < 8; ++i) {
      while (__hip_atomic_load(&flags[b][i], __ATOMIC_ACQUIRE,
                               __HIP_MEMORY_SCOPE_WORKGROUP) < needtag) { }
      __builtin_amdgcn_sched_barrier(0);
      const int base = i * 128 + g_ * 16;
      #pragma unroll
      for (int j = 0; j < 4; ++j) {
        const u32x4 qq = *reinterpret_cast<const u32x4*>(&lds[b][swz3(base + 4 * j)]);
        ac0 = dot2f(qq[0], w2[i][4*j+0], ac0);
        ac1 = dot2f(qq[1], w2[i][4*j+1], ac1);
        ac2 = dot2f(qq[2], w2[i][4*j+2], ac2);
        ac3 = dot2f(qq[3], w2[i][4*j+3], ac3);
      }
    }
    float p = (ac0 + ac1) + (ac2 + ac3);
    // fold over g (bits 3,4,5): lane l ends with row (l&7) total
    p += __shfl_xor(p, 8, 64);
    p += __shfl_xor(p, 16, 64);
    p += __shfl_xor(p, 32, 64);

    // ---- WAR gate: fires ~every NSLOT-1 steps ----
    if (t >= NSLOT - 1) {
      const uint32_t need = (uint32_t)(t + 2 - NSLOT);
      if (need > prog_seen) {
        for (;;) {
          uint32_t mn = __hip_atomic_load(&progress[lane & (NWORK - 1)],
                            __ATOMIC_RELAXED, __HIP_MEMORY_SCOPE_AGENT);
          uint32_t qv;
          qv = (uint32_t)__shfl_xor((int)mn, 1, 64);  mn = umin32(mn, qv);
          qv = (uint32_t)__shfl_xor((int)mn, 2, 64);  mn = umin32(mn, qv);
          qv = (uint32_t)__shfl_xor((int)mn, 4, 64);  mn = umin32(mn, qv);
          qv = (uint32_t)__shfl_xor((int)mn, 8, 64);  mn = umin32(mn, qv);
          qv = (uint32_t)__shfl_xor((int)mn, 16, 64); mn = umin32(mn, qv);
          if (mn >= need) { prog_seen = mn; break; }
          __builtin_amdgcn_s_sleep(1);
        }
      }
    }

    // ---- x for this step via one bpermute (window regs, no VMEM) ----
    const float xsrc = (off < 8) ? xa : xb;
    const float xvt  = __shfl(xsrc, ((off & 7) << 3) | xr, 64);

    // ---- state update: publish act FIRST, then out[] store ----
    if (lane < RPW) {
      v = 0.9f * v + 0.1f * (p + xvt);
      const float a = 1.0f / (1.0f + __expf(-(v + bj)));
      __half h = __float2half_rn(a);
      uint16_t hb; __builtin_memcpy(&hb, &h, 2);
      const uint32_t e = ((uint32_t)(t + 2) << 16) | hb;
      __hip_atomic_store(&actbuf[(size_t)((t + 1) & (NSLOT - 1)) * DIM + row0 + lane], e,
                         __ATOMIC_RELAXED, __HIP_MEMORY_SCOPE_AGENT);
      out[(size_t)(t + 1) * DIM + row0 + lane] = v;
    }

    // ---- window swap after last use ----
    if (off == 15) { t0 += 16; xa = xa2; xb = xb2; }

    // ---- end-of-step barrier: bounds intra-block drift, WAR safety for
    //      lds[b]/flags[b] reuse at t+2 ----
    __syncthreads();
  }
}

extern "C" void kernel_launch(void* const* d_in, const int* in_sizes, int n_in,
                              void* d_out, int out_size, void* d_ws, size_t ws_size,
                              hipStream_t stream) {
  const float* x       = (const float*)d_in[0];
  const float* W       = (const float*)d_in[1];
  const float* bias    = (const float*)d_in[2];
  const float* initial = (const float*)d_in[3];
  float* out           = (float*)d_out;

  uint32_t* actbuf = (uint32_t*)d_ws;

  const size_t need16 = ((size_t)16 * DIM + NWORK + NBLK) * 4;
  const size_t need8  = ((size_t)8  * DIM + NWORK + NBLK) * 4;
  void* kfun;
  size_t ringwords;
  if (ws_size >= need16)     { kfun = (void*)ctrnn_kernel<16>; ringwords = (size_t)16 * DIM; }
  else if (ws_size >= need8) { kfun = (void*)ctrnn_kernel<8>;  ringwords = (size_t)8  * DIM; }
  else                       { kfun = (void*)ctrnn_kernel<2>;  ringwords = (size_t)2  * DIM; }

  uint32_t* progress = actbuf + ringwords;
  uint32_t* xccmap   = progress + NWORK;

  // Tags/progress are generation counters — clear every call (capture-safe).
  hipMemsetAsync(d_ws, 0, (ringwords + NWORK + NBLK) * 4, stream);

  void* args[] = { (void*)&x, (void*)&W, (void*)&bias, (void*)&initial,
                   (void*)&out, (void*)&actbuf, (void*)&progress, (void*)&xccmap };
  hipLaunchCooperativeKernel(kfun, dim3(NBLK), dim3(NTH), args, 0, stream);
}

// Round 17
// 9043.831 us; speedup vs baseline: 5.8218x; 2.5782x over previous
//
#include <hip/hip_runtime.h>
#include <hip/hip_fp16.h>
#include <hip/hip_cooperative_groups.h>
#include <stdint.h>

#define TIME_STEPS 4096
#define DIM        2048
#define NBLK       256    // grid (co-resident: 1 block/CU)
#define NTH        512    // 8 waves per block
#define NWORK      32     // worker blocks (one XCD's worth of CUs)
#define WVB        8      // waves per worker block
#define RPW        8      // rows per wave: 256 waves x 8 = 2048

typedef uint32_t u32x4 __attribute__((ext_vector_type(4)));
typedef _Float16 h2f16 __attribute__((ext_vector_type(2)));

// actbuf entry: u32 = (tag16<<16)|fp16bits(act); slot t%NSLOT holds gen t
// (tag=t+1). Validity: min over dwords >= tag<<16.
// r17 = r14 restored (best measured: 9.04ms) + NSLOT=16 tier.
// Structure: 2-deep ping-pong poll (fresh snapshot every ~half RT);
// row-per-lane dot (3-shuffle reduce); swz2 conflict-free LDS; x batched
// 16 steps ahead in regs; publish act before out[].
// d_ws: ring | progress[NWORK] | xccmap[NBLK]

__device__ __forceinline__ uint32_t umin32(uint32_t a, uint32_t b) { return a < b ? a : b; }

__device__ __forceinline__ float dot2f(uint32_t packed, h2f16 w, float acc) {
#if __has_builtin(__builtin_amdgcn_fdot2)
  return __builtin_amdgcn_fdot2(__builtin_bit_cast(h2f16, packed), w, acc, false);
#else
  h2f16 a = __builtin_bit_cast(h2f16, packed);
  acc = fmaf((float)a.x, (float)w.x, acc);
  return fmaf((float)a.y, (float)w.y, acc);
#endif
}

// Pair-index swizzle: xor bank bits [4:2] with producer-wave bits [9:7].
// Preserves low 2 bits (b128 contiguity); the reader's 8 col-groups
// (stride 128 pairs) land on 8 distinct bank quads -> conflict-free (r14: 0).
__device__ __forceinline__ int swz2(int p) { return p ^ (((p >> 7) & 7) << 2); }

#define POLL_ISSUE(dst, src)                                       \
  asm volatile("global_load_dwordx4 %0, %1, off sc1"               \
               : "=&v"(dst) : "v"(src) : "memory")

template<int NSLOT>
__global__ __launch_bounds__(NTH, 2) void ctrnn_kernel(
    const float* __restrict__ x,        // [TIME, DIM]
    const float* __restrict__ W,        // [DIM, DIM]
    const float* __restrict__ bias,     // [DIM]
    const float* __restrict__ initial,  // [DIM]
    float* __restrict__ out,            // [TIME, DIM]
    uint32_t* __restrict__ actbuf,
    uint32_t* __restrict__ progress,
    uint32_t* __restrict__ xccmap)
{
  const int tid  = threadIdx.x;
  const int lane = tid & 63;
  const int wv   = tid >> 6;            // wave in block (0..7)

  // ---- phase 0: report this block's XCD ----
  if (tid == 0) {
    uint32_t xcc;
    asm volatile("s_getreg_b32 %0, hwreg(HW_REG_XCC_ID)" : "=s"(xcc));
    __hip_atomic_store(&xccmap[blockIdx.x], xcc,
                       __ATOMIC_RELAXED, __HIP_MEMORY_SCOPE_AGENT);
  }
  cooperative_groups::this_grid().sync();

  // ---- phase 1: deterministic election (bijective rank permutation) ----
  __shared__ uint32_t s_map[NBLK];
  for (int i = tid; i < NBLK; i += NTH)
    s_map[i] = __hip_atomic_load(&xccmap[i], __ATOMIC_RELAXED, __HIP_MEMORY_SCOPE_AGENT);
  __syncthreads();
  const uint32_t target = s_map[0];
  int before = 0, total = 0, beforeN = 0;
  const int bid = blockIdx.x;
  for (int i = 0; i < NBLK; ++i) {
    const bool m = (s_map[i] == target);
    total += m;
    if (i < bid) { before += m; beforeN += !m; }
  }
  const bool mine = (s_map[bid] == target);
  const int rank = mine ? before : (total + beforeN);
  if (rank >= NWORK) return;            // 224 blocks exit; no further grid syncs
  const int wb = rank;

  __shared__ uint32_t lds[2][1024];     // packed fp16-pair acts, swz2 layout

  const int gwid = wb * WVB + wv;       // worker wave id 0..255
  const int row0 = gwid * RPW;

  // Row-per-lane layout: lane = (c<<3)|r; row = row0+r, cols [c*256,(c+1)*256).
  const int r_ = lane & 7;
  const int c_ = lane >> 3;

  // W fragment fp16x2: 1 row x 256 cols = 128 VGPRs (all indices static).
  h2f16 w2[128];
  {
    const float* wr = W + (size_t)(row0 + r_) * DIM + c_ * 256;
    #pragma unroll
    for (int q = 0; q < 128; ++q)
      w2[q] = h2f16{(_Float16)wr[2*q], (_Float16)wr[2*q+1]};
  }

  // ---- batched x window: [t0, t0+16), 2 VGPRs/lane ----
  const int xq = lane >> 3, xr = lane & 7;
  float xa = x[(size_t)xq * DIM + row0 + xr];
  float xb = x[(size_t)(8 + xq) * DIM + row0 + xr];
  float xa2 = 0.f, xb2 = 0.f;
  int t0 = 0;

  // State: lanes 0..7 own rows row0..row0+7.
  float v = 0.f, bj = 0.f;
  if (lane < RPW) {
    const int j = row0 + lane;
    v  = initial[j];
    bj = bias[j];
    out[j] = v;
    const float a0 = 1.0f / (1.0f + __expf(-(v + bj)));
    __half h = __float2half_rn(a0);
    uint16_t hb; __builtin_memcpy(&hb, &h, 2);
    __hip_atomic_store(&actbuf[j], (1u << 16) | hb,
                       __ATOMIC_RELAXED, __HIP_MEMORY_SCOPE_AGENT);
  }

  // Staging geometry: wave wv owns entries [wv*256, +256); lane's quad at e0.
  const int e0 = wv * 256 + lane * 4;
  const int p0 = e0 >> 1;              // even pair index

  uint32_t prog_seen = 0;

  for (int t = 0; t < TIME_STEPS - 1; ++t) {
    const int b = t & 1;
    const int off = t - t0;
    const uint32_t needtag = (uint32_t)(t + 1);
    const uint32_t thresh  = needtag << 16;

    // ---- 2-deep ping-pong poll (sc1); per-lane early exit ----
    const uint32_t* qsrc = actbuf + (size_t)(t & (NSLOT - 1)) * DIM + e0;
    u32x4 qa, qb, q;
    POLL_ISSUE(qa, qsrc);
    POLL_ISSUE(qb, qsrc);
    for (;;) {
      asm volatile("s_waitcnt vmcnt(1)" ::: "memory");   // qa landed
      __builtin_amdgcn_sched_barrier(0);
      if (umin32(umin32(qa[0], qa[1]), umin32(qa[2], qa[3])) >= thresh) { q = qa; break; }
      POLL_ISSUE(qa, qsrc);
      asm volatile("s_waitcnt vmcnt(1)" ::: "memory");   // qb landed
      __builtin_amdgcn_sched_barrier(0);
      if (umin32(umin32(qb[0], qb[1]), umin32(qb[2], qb[3])) >= thresh) { q = qb; break; }
      POLL_ISSUE(qb, qsrc);
    }
    asm volatile("s_waitcnt vmcnt(0)" ::: "memory");     // retire strays (reg reuse)
    __builtin_amdgcn_sched_barrier(0);

    // ---- stage packed fp16 pairs into swz2 LDS ----
    {
      const uint32_t lo = __builtin_amdgcn_perm(q[1], q[0], 0x05040100u);
      const uint32_t hi = __builtin_amdgcn_perm(q[3], q[2], 0x05040100u);
      const int w0 = swz2(p0);
      lds[b][w0]     = lo;
      lds[b][w0 + 1] = hi;
    }

    __syncthreads();  // slot t fully staged in lds[b]

    if (tid == 0)
      __hip_atomic_store(&progress[wb], needtag,
                         __ATOMIC_RELAXED, __HIP_MEMORY_SCOPE_AGENT);

    // ---- x window refill (once per 16 steps) ----
    if (off == 13) {
      const int ta = min(t0 + 16 + xq, TIME_STEPS - 1);
      const int tb = min(t0 + 24 + xq, TIME_STEPS - 1);
      xa2 = x[(size_t)ta * DIM + row0 + xr];
      xb2 = x[(size_t)tb * DIM + row0 + xr];
    }

    // ---- dot: row r_ over cols [c_*256, +256): 32 b128 reads (8-lane
    //      broadcast, conflict-free), 128 dot2 into 4 chains ----
    float ac0 = 0.f, ac1 = 0.f, ac2 = 0.f, ac3 = 0.f;
    const int cbase = c_ * 128;
    #pragma unroll
    for (int j = 0; j < 32; ++j) {
      const u32x4 qq = *reinterpret_cast<const u32x4*>(&lds[b][swz2(cbase + 4 * j)]);
      ac0 = dot2f(qq[0], w2[4*j+0], ac0);
      ac1 = dot2f(qq[1], w2[4*j+1], ac1);
      ac2 = dot2f(qq[2], w2[4*j+2], ac2);
      ac3 = dot2f(qq[3], w2[4*j+3], ac3);
    }
    float p = (ac0 + ac1) + (ac2 + ac3);
    // fold over c (bits 3,4,5): lane l ends with row (l&7) total
    p += __shfl_xor(p, 8, 64);
    p += __shfl_xor(p, 16, 64);
    p += __shfl_xor(p, 32, 64);

    // ---- WAR gate: fires ~every NSLOT-1 steps ----
    if (t >= NSLOT - 1) {
      const uint32_t need = (uint32_t)(t + 2 - NSLOT);
      if (need > prog_seen) {
        for (;;) {
          uint32_t mn = __hip_atomic_load(&progress[lane & (NWORK - 1)],
                            __ATOMIC_RELAXED, __HIP_MEMORY_SCOPE_AGENT);
          uint32_t qv;
          qv = (uint32_t)__shfl_xor((int)mn, 1, 64);  mn = umin32(mn, qv);
          qv = (uint32_t)__shfl_xor((int)mn, 2, 64);  mn = umin32(mn, qv);
          qv = (uint32_t)__shfl_xor((int)mn, 4, 64);  mn = umin32(mn, qv);
          qv = (uint32_t)__shfl_xor((int)mn, 8, 64);  mn = umin32(mn, qv);
          qv = (uint32_t)__shfl_xor((int)mn, 16, 64); mn = umin32(mn, qv);
          if (mn >= need) { prog_seen = mn; break; }
          __builtin_amdgcn_s_sleep(1);
        }
      }
    }

    // ---- x for this step via one shuffle (window regs, no VMEM) ----
    const float xsrc = (off < 8) ? xa : xb;
    const float xvt  = __shfl(xsrc, ((off & 7) << 3) | xr, 64);

    // ---- state update: publish act FIRST, then out[] store ----
    if (lane < RPW) {
      v = 0.9f * v + 0.1f * (p + xvt);
      const float a = 1.0f / (1.0f + __expf(-(v + bj)));
      __half h = __float2half_rn(a);
      uint16_t hb; __builtin_memcpy(&hb, &h, 2);
      const uint32_t e = ((uint32_t)(t + 2) << 16) | hb;
      __hip_atomic_store(&actbuf[(size_t)((t + 1) & (NSLOT - 1)) * DIM + row0 + lane], e,
                         __ATOMIC_RELAXED, __HIP_MEMORY_SCOPE_AGENT);
      out[(size_t)(t + 1) * DIM + row0 + lane] = v;
    }

    // ---- window swap after last use ----
    if (off == 15) { t0 += 16; xa = xa2; xb = xb2; }
  }
}

extern "C" void kernel_launch(void* const* d_in, const int* in_sizes, int n_in,
                              void* d_out, int out_size, void* d_ws, size_t ws_size,
                              hipStream_t stream) {
  const float* x       = (const float*)d_in[0];
  const float* W       = (const float*)d_in[1];
  const float* bias    = (const float*)d_in[2];
  const float* initial = (const float*)d_in[3];
  float* out           = (float*)d_out;

  uint32_t* actbuf = (uint32_t*)d_ws;

  const size_t need16 = ((size_t)16 * DIM + NWORK + NBLK) * 4;
  const size_t need8  = ((size_t)8  * DIM + NWORK + NBLK) * 4;
  void* kfun;
  size_t ringwords;
  if (ws_size >= need16)     { kfun = (void*)ctrnn_kernel<16>; ringwords = (size_t)16 * DIM; }
  else if (ws_size >= need8) { kfun = (void*)ctrnn_kernel<8>;  ringwords = (size_t)8  * DIM; }
  else                       { kfun = (void*)ctrnn_kernel<2>;  ringwords = (size_t)2  * DIM; }

  uint32_t* progress = actbuf + ringwords;
  uint32_t* xccmap   = progress + NWORK;

  // Tags/progress are generation counters — clear every call (capture-safe).
  hipMemsetAsync(d_ws, 0, (ringwords + NWORK + NBLK) * 4, stream);

  void* args[] = { (void*)&x, (void*)&W, (void*)&bias, (void*)&initial,
                   (void*)&out, (void*)&actbuf, (void*)&progress, (void*)&xccmap };
  hipLaunchCooperativeKernel(kfun, dim3(NBLK), dim3(NTH), args, 0, stream);
}